// Round 1
// baseline (1987.020 us; speedup 1.0000x reference)
//
#include <hip/hip_runtime.h>
#include <hip/hip_bf16.h>
#include <stdint.h>

#define LN_EPS 1e-5f
#define UPDATE_BIAS_ -1.0f

// Problem dims (fixed by the reference)
#define B_   8192
#define IN_  2048
#define H_   4096
#define K_   (IN_ + H_)   // 6144
#define N3_  (3 * H_)     // 12288

typedef unsigned short ushort_t;
typedef __attribute__((ext_vector_type(8))) short bf16x8;   // 8 bf16 in 4 VGPRs
typedef __attribute__((ext_vector_type(4))) float f32x4;

// ---------- helpers ----------
__device__ static inline uint32_t f2bf_bits(float f) {
    union { float f; uint32_t u; } v; v.f = f;
    return (v.u + 0x7FFFu + ((v.u >> 16) & 1u)) >> 16;   // RNE to bf16
}
__device__ static inline uint32_t pack2(float a, float b) {
    return f2bf_bits(a) | (f2bf_bits(b) << 16);
}
__device__ static inline float bf2f(uint32_t bits16) {   // bits16 = bf16 bits in low 16
    union { uint32_t u; float f; } v; v.u = bits16 << 16;
    return v.f;
}
__device__ static inline void async_cp16(const ushort_t* g, ushort_t* l) {
    __builtin_amdgcn_global_load_lds(
        (const __attribute__((address_space(1))) void*)g,
        (__attribute__((address_space(3))) void*)l, 16, 0, 0);
}

// ---------- kernel 1: W fp32 -> bf16 ----------
__global__ __launch_bounds__(256) void conv_w(const float* __restrict__ W,
                                              ushort_t* __restrict__ Wb) {
    // total elems = N3_*K_ = 75,497,472; each thread converts 8
    long long idx = (long long)blockIdx.x * 256 + threadIdx.x;
    const float* src = W + idx * 8;
    float4 lo = ((const float4*)src)[0];
    float4 hi = ((const float4*)src)[1];
    uint4 o;
    o.x = pack2(lo.x, lo.y); o.y = pack2(lo.z, lo.w);
    o.z = pack2(hi.x, hi.y); o.w = pack2(hi.z, hi.w);
    ((uint4*)(Wb + idx * 8))[0] = o;
}

// ---------- kernel 2: concat(inputs,state) fp32 -> bf16 ----------
__global__ __launch_bounds__(256) void conv_xh(const float* __restrict__ inp,
                                               const float* __restrict__ st,
                                               ushort_t* __restrict__ xh) {
    long long idx = (long long)blockIdx.x * 256 + threadIdx.x; // B_*768 threads
    int row = (int)(idx / (K_ / 8));
    int c8  = (int)(idx % (K_ / 8)) * 8;
    const float* src = (c8 < IN_) ? (inp + (long long)row * IN_ + c8)
                                  : (st  + (long long)row * H_  + (c8 - IN_));
    float4 lo = ((const float4*)src)[0];
    float4 hi = ((const float4*)src)[1];
    uint4 o;
    o.x = pack2(lo.x, lo.y); o.y = pack2(lo.z, lo.w);
    o.z = pack2(hi.x, hi.y); o.w = pack2(hi.z, hi.w);
    ((uint4*)(xh + (long long)row * K_ + c8))[0] = o;
}

// ---------- kernel 3: C[M,N] = A[M,K] * W[N,K]^T   (bf16 in, bf16 out) ----------
// m97 structure: 128x128 tile, BK=64, 256 threads = 4 waves, each wave 64x64.
__global__ __launch_bounds__(256, 2) void gemm_bt(const ushort_t* __restrict__ A,
                                                  const ushort_t* __restrict__ W,
                                                  ushort_t* __restrict__ C) {
    __shared__ ushort_t As[128 * 64];   // 16 KB
    __shared__ ushort_t Bs[128 * 64];   // 16 KB

    const int tid   = threadIdx.x;
    const int tileN = blockIdx.x * 128;
    const int tileM = blockIdx.y * 128;

    // staging: thread t loads 16B; rows t>>3 (+32*r), cols (t&7)*8
    const int srow = tid >> 3;          // 0..31
    const int scol = (tid & 7) * 8;     // 0..56
    const ushort_t* gA = A + (size_t)(tileM + srow) * K_ + scol;
    const ushort_t* gB = W + (size_t)(tileN + srow) * K_ + scol;
    ushort_t* lA = &As[srow * 64 + scol];
    ushort_t* lB = &Bs[srow * 64 + scol];

    const int lane = tid & 63;
    const int wv = tid >> 6;
    const int wm = (wv & 1) * 64;
    const int wn = (wv >> 1) * 64;
    const int lr = lane & 15;           // row-in-16 (A: m, B: n, C: col)
    const int lq = lane >> 4;           // quad 0..3

    f32x4 acc[4][4];
#pragma unroll
    for (int i = 0; i < 4; ++i)
#pragma unroll
        for (int j = 0; j < 4; ++j) acc[i][j] = (f32x4){0.f, 0.f, 0.f, 0.f};

    for (int k0 = 0; k0 < K_; k0 += 64) {
        __syncthreads();   // previous compute done before overwriting LDS
#pragma unroll
        for (int r = 0; r < 4; ++r)
            async_cp16(gA + (size_t)r * 32 * K_ + k0, lA + r * 32 * 64);
#pragma unroll
        for (int r = 0; r < 4; ++r)
            async_cp16(gB + (size_t)r * 32 * K_ + k0, lB + r * 32 * 64);
        __syncthreads();   // compiler drains vmcnt before barrier

#pragma unroll
        for (int kk = 0; kk < 2; ++kk) {
            bf16x8 af[4], bfg[4];
#pragma unroll
            for (int i = 0; i < 4; ++i)
                af[i] = *(const bf16x8*)&As[(wm + i * 16 + lr) * 64 + kk * 32 + lq * 8];
#pragma unroll
            for (int j = 0; j < 4; ++j)
                bfg[j] = *(const bf16x8*)&Bs[(wn + j * 16 + lr) * 64 + kk * 32 + lq * 8];
#pragma unroll
            for (int i = 0; i < 4; ++i)
#pragma unroll
                for (int j = 0; j < 4; ++j)
                    acc[i][j] = __builtin_amdgcn_mfma_f32_16x16x32_bf16(
                        af[i], bfg[j], acc[i][j], 0, 0, 0);
        }
    }

    // epilogue: C/D layout col=lane&15, row=(lane>>4)*4+reg  [m89-verified]
#pragma unroll
    for (int i = 0; i < 4; ++i)
#pragma unroll
        for (int j = 0; j < 4; ++j)
#pragma unroll
            for (int r = 0; r < 4; ++r) {
                int rrow = tileM + wm + i * 16 + lq * 4 + r;
                int ccol = tileN + wn + j * 16 + lr;
                C[(size_t)rrow * N3_ + ccol] = (ushort_t)f2bf_bits(acc[i][j][r]);
            }
}

// ---------- kernel 4: LayerNorm over 3H + GRU gates ----------
__global__ __launch_bounds__(256) void ln_gru(const ushort_t* __restrict__ parts,
                                              const float* __restrict__ state,
                                              const float* __restrict__ bias,
                                              const float* __restrict__ gamma,
                                              const float* __restrict__ beta,
                                              float* __restrict__ out) {
    __shared__ float row[N3_];          // 48 KB
    __shared__ float wsum[4], wsum2[4];
    const int tid = threadIdx.x;
    const int r   = blockIdx.x;
    const ushort_t* p = parts + (size_t)r * N3_;

    float s = 0.f, ss = 0.f;
#pragma unroll
    for (int u = 0; u < 6; ++u) {
        int base = (u * 256 + tid) * 8;
        uint4 raw = *(const uint4*)(p + base);
        float v[8];
        v[0] = bf2f(raw.x & 0xFFFFu); v[1] = bf2f(raw.x >> 16);
        v[2] = bf2f(raw.y & 0xFFFFu); v[3] = bf2f(raw.y >> 16);
        v[4] = bf2f(raw.z & 0xFFFFu); v[5] = bf2f(raw.z >> 16);
        v[6] = bf2f(raw.w & 0xFFFFu); v[7] = bf2f(raw.w >> 16);
#pragma unroll
        for (int k = 0; k < 8; ++k) {
            float val = v[k] + bias[base + k];
            s += val; ss += val * val;
            row[base + k] = val;
        }
    }
    // wave reduce (64 lanes)
#pragma unroll
    for (int off = 32; off > 0; off >>= 1) {
        s  += __shfl_down(s, off);
        ss += __shfl_down(ss, off);
    }
    if ((tid & 63) == 0) { wsum[tid >> 6] = s; wsum2[tid >> 6] = ss; }
    __syncthreads();
    float S  = wsum[0] + wsum[1] + wsum[2] + wsum[3];
    float SS = wsum2[0] + wsum2[1] + wsum2[2] + wsum2[3];
    float mu   = S * (1.0f / N3_);
    float var  = SS * (1.0f / N3_) - mu * mu;
    float rstd = rsqrtf(var + LN_EPS);

    const float* st = state + (size_t)r * H_;
    float* o = out + (size_t)r * H_;
#pragma unroll
    for (int u = 0; u < 16; ++u) {
        int c = u * 256 + tid;
        float y0 = (row[c]          - mu) * rstd * gamma[c]          + beta[c];
        float y1 = (row[c + H_]     - mu) * rstd * gamma[c + H_]     + beta[c + H_];
        float y2 = (row[c + 2*H_]   - mu) * rstd * gamma[c + 2*H_]   + beta[c + 2*H_];
        float rg = 1.0f / (1.0f + __expf(-y0));
        float x  = rg * y1;
        float e2 = __expf(2.0f * x);
        float cd = (e2 - 1.0f) / (e2 + 1.0f);
        float up = 1.0f / (1.0f + __expf(-(y2 + UPDATE_BIAS_)));
        o[c] = up * cd + (1.0f - up) * st[c];
    }
}

// ---------- launcher ----------
extern "C" void kernel_launch(void* const* d_in, const int* in_sizes, int n_in,
                              void* d_out, int out_size, void* d_ws, size_t ws_size,
                              hipStream_t stream) {
    const float* inputs = (const float*)d_in[0];
    const float* state  = (const float*)d_in[1];
    const float* W      = (const float*)d_in[2];
    const float* b      = (const float*)d_in[3];
    const float* gamma  = (const float*)d_in[4];
    const float* beta   = (const float*)d_in[5];
    float* out = (float*)d_out;

    // workspace layout (bf16): Wb [N3_,K_] | xh [B_,K_] | parts [B_,N3_]
    const size_t nWb = (size_t)N3_ * K_;
    const size_t nXh = (size_t)B_ * K_;
    const size_t nPt = (size_t)B_ * N3_;
    const size_t need = (nWb + nXh + nPt) * sizeof(ushort_t);
    if (ws_size < need) return;  // clean fail; will chunk M if this triggers

    ushort_t* Wb    = (ushort_t*)d_ws;
    ushort_t* xh    = Wb + nWb;
    ushort_t* parts = xh + nXh;

    conv_w <<<dim3((unsigned)(nWb / 8 / 256)), dim3(256), 0, stream>>>(W, Wb);
    conv_xh<<<dim3((unsigned)(nXh / 8 / 256)), dim3(256), 0, stream>>>(inputs, state, xh);
    gemm_bt<<<dim3(N3_ / 128, B_ / 128), dim3(256), 0, stream>>>(xh, Wb, parts);
    ln_gru <<<dim3(B_), dim3(256), 0, stream>>>(parts, state, b, gamma, beta, out);
}